// Round 7
// baseline (20626.524 us; speedup 1.0000x reference)
//
#include <hip/hip_runtime.h>
#include <hip/hip_bf16.h>
#include <math.h>

#define B_ 64
#define T_ 1024
#define D_ 512
#define H_ 512
#define M_ 256
#define CC 63
#define SS 64
#define NBLK 1024
#define INV_SQRT_2PI 0.3989422804014327f

typedef __attribute__((ext_vector_type(8))) short short8v;

static __device__ __forceinline__ float bf2f(unsigned short u) {
    unsigned int x = ((unsigned int)u) << 16;
    return __uint_as_float(x);
}
static __device__ __forceinline__ unsigned short f2bf(float f) {
    unsigned int x = __float_as_uint(f);
    unsigned int r = (x + 0x7fff + ((x >> 16) & 1)) >> 16;
    return (unsigned short)r;
}
static __device__ __forceinline__ float sigm(float x) {
    return 1.f / (1.f + __expf(-x));
}
static __device__ __forceinline__ float wsum64(float v) {
    for (int o = 32; o > 0; o >>= 1) v += __shfl_xor(v, o, 64);
    return v;
}

// ---- coherent (agent-scope, write-through / L2-bypass) accessors ----
static __device__ __forceinline__ float cload(const float* p) {
    return __hip_atomic_load(p, __ATOMIC_RELAXED, __HIP_MEMORY_SCOPE_AGENT);
}
static __device__ __forceinline__ void cstore(float* p, float v) {
    __hip_atomic_store(p, v, __ATOMIC_RELAXED, __HIP_MEMORY_SCOPE_AGENT);
}
static __device__ __forceinline__ int cloadi(const int* p) {
    return __hip_atomic_load(p, __ATOMIC_RELAXED, __HIP_MEMORY_SCOPE_AGENT);
}
static __device__ __forceinline__ void cstorei(int* p, int v) {
    __hip_atomic_store(p, v, __ATOMIC_RELAXED, __HIP_MEMORY_SCOPE_AGENT);
}
static __device__ __forceinline__ float2 cload2(const float* p) {
    union { unsigned long long u64; float2 f2; } cv;
    cv.u64 = __hip_atomic_load((const unsigned long long*)p, __ATOMIC_RELAXED, __HIP_MEMORY_SCOPE_AGENT);
    return cv.f2;
}

// fence-free tree barrier: 16 groups x 64 blocks; relaxed agent atomics only.
// Data exchanged between phases is written via cstore* (write-through), so no
// L2 writeback/invalidate is required; __syncthreads drains vmcnt pre-arrive.
static __device__ __forceinline__ void gbar(int* bar, int& epoch) {
    epoch += 1;
    __syncthreads();
    if (threadIdx.x == 0) {
        int gid = blockIdx.x >> 6;
        int v = __hip_atomic_fetch_add(bar + gid * 32, 1, __ATOMIC_RELAXED, __HIP_MEMORY_SCOPE_AGENT);
        if (v == epoch * 64 - 1) {
            int g = __hip_atomic_fetch_add(bar + 1024, 1, __ATOMIC_RELAXED, __HIP_MEMORY_SCOPE_AGENT);
            if (g == epoch * 16 - 1) {
#pragma unroll
                for (int i = 0; i < 16; ++i)
                    __hip_atomic_store(bar + 512 + i * 32, epoch, __ATOMIC_RELAXED, __HIP_MEMORY_SCOPE_AGENT);
            }
        }
        while (__hip_atomic_load(bar + 512 + gid * 32, __ATOMIC_RELAXED, __HIP_MEMORY_SCOPE_AGENT) < epoch)
            __builtin_amdgcn_s_sleep(2);
        asm volatile("" ::: "memory");
    }
    __syncthreads();
}

// ---------------- prologue kernels (proven) ----------------

__global__ __launch_bounds__(256) void k_conv(const float* __restrict__ src,
        unsigned short* __restrict__ dst, int n4) {
    int stride = gridDim.x * 256;
    for (int i = blockIdx.x * 256 + threadIdx.x; i < n4; i += stride) {
        float4 v = ((const float4*)src)[i];
        ushort4 o;
        o.x = f2bf(v.x); o.y = f2bf(v.y); o.z = f2bf(v.z); o.w = f2bf(v.w);
        ((ushort4*)dst)[i] = o;
    }
}

__global__ __launch_bounds__(256) void k_gemm(const float* __restrict__ Lf,
        const float* __restrict__ psiw, const float* __restrict__ psib,
        float* __restrict__ clT) {
    __shared__ float At[64 * 65];
    __shared__ float Bt[64 * 65];
    int tid = threadIdx.x;
    int pt = blockIdx.x >> 2;
    int mt = blockIdx.x & 3;
    int p0 = pt * 64, m0 = mt * 64;
    int tp = tid >> 4, tm = tid & 15;
    float acc[4][4] = {{0.f}};
    for (int k0 = 0; k0 < 512; k0 += 64) {
        __syncthreads();
        for (int i = 0; i < 16; ++i) {
            int lidx = i * 256 + tid;
            int r = lidx >> 6, c = lidx & 63;
            At[r * 65 + c] = Lf[(size_t)(p0 + r) * 512 + k0 + c];
            Bt[r * 65 + c] = psiw[(size_t)(m0 + r) * 512 + k0 + c];
        }
        __syncthreads();
        for (int dk = 0; dk < 64; ++dk) {
            float av[4], bv[4];
#pragma unroll
            for (int i = 0; i < 4; ++i) av[i] = At[(4 * tp + i) * 65 + dk];
#pragma unroll
            for (int j = 0; j < 4; ++j) bv[j] = Bt[(4 * tm + j) * 65 + dk];
#pragma unroll
            for (int i = 0; i < 4; ++i)
#pragma unroll
                for (int j = 0; j < 4; ++j)
                    acc[i][j] = fmaf(av[i], bv[j], acc[i][j]);
        }
    }
#pragma unroll
    for (int i = 0; i < 4; ++i) {
        int p = p0 + 4 * tp + i;
        int b = p >> 10, t = p & 1023;
#pragma unroll
        for (int j = 0; j < 4; ++j) {
            int m = m0 + 4 * tm + j;
            clT[((size_t)(b * 256 + m)) * 1024 + t] = fmaxf(acc[i][j] + psib[m], 0.f);
        }
    }
}

// ---------------- persistent mega kernel, 1024 blocks, fence-free ----------------

__global__ __launch_bounds__(256, 4) void k_mega(
        const unsigned short* __restrict__ Lbf, const float* __restrict__ Lf,
        const float* __restrict__ gt,
        const float* __restrict__ phiw, const float* __restrict__ phib,
        const float* __restrict__ wih0, const float* __restrict__ whh0,
        const float* __restrict__ bih0, const float* __restrict__ bhh0,
        const float* __restrict__ wih1, const float* __restrict__ whh1,
        const float* __restrict__ bih1, const float* __restrict__ bhh1,
        const float* __restrict__ charw, const float* __restrict__ charb,
        const float* __restrict__ clT,
        float* gtT, float* h0buf, float* h1buf, float* h1bb,
        float* ctxT, float* ctxb, float* energyT, float* vbuf,
        float* logit, int* colZero, int* bar,
        float* preds, float* atts) {
    __shared__ __align__(16) float smem[6464];   // 25.9 KB overlay

    int tid = threadIdx.x, blk = blockIdx.x;
    int epoch = 0;
    int role = blk & 7;
    float c0reg = 0.f, c1reg = 0.f;   // persistent cell state (register-resident)

    // ---- INIT: gtT (write-once, coherent stores), state zero, ctx(=L[:,0,:]) ----
    if (blk < 64) {
        int s0 = blk;
        for (int r = tid; r < CC * 64; r += 256) {
            int k = r >> 6, b = r & 63;
            cstore(&gtT[s0 * (CC * 64) + r], gt[(b * SS + s0) * CC + k]);
        }
    } else if (blk < 192) {
        int idx = (blk - 64) * 256 + tid;
        cstore(&h0buf[idx], 0.f);
        cstore(&h1buf[idx], 0.f);
        int d = idx >> 6, b = idx & 63;
        float v = Lf[(size_t)b * (T_ * D_) + d];
        cstore(&ctxT[idx], v);
        cstore(&ctxb[b * 512 + d], v);
    }
    gbar(bar, epoch);

    for (int s = 0; s < SS; ++s) {
        int pin = s & 1;
        const float* h0in = h0buf + pin * 32768;
        float* h0out = h0buf + (1 - pin) * 32768;
        const float* h1in = h1buf + pin * 32768;
        float* h1out = h1buf + (1 - pin) * 32768;
        const float* h1b_prev = h1bb + pin * 32768;
        float* h1b_cur = h1bb + (1 - pin) * 32768;

        // ==== phase A: LSTM0 (role 0, 128 blocks x 4 units) || char-logits(s-1) (role 1) ====
        if (role == 0) {
            int uid = blk >> 3;                  // 0..127
            float* xs = smem;                    // [64 k][64 b]
            float* ws = smem + 4096;             // [16 r][68]
            float* ex = smem + 5184;             // [16 r][64 b]
            int r = tid >> 4, tb = tid & 15;
            float a0 = 0.f, a1 = 0.f, a2 = 0.f, a3 = 0.f;
            for (int kc = 0; kc < 17; ++kc) {
                int k0 = kc * 64;
                __syncthreads();
#pragma unroll
                for (int i = 0; i < 8; ++i) {
                    int e2 = i * 256 + tid;
                    int kk = e2 >> 5, b2 = (e2 & 31) * 2;
                    int k = k0 + kk;
                    float2 v;
                    if (k < 63) {
                        if (s > 0) v = *(const float2*)&gtT[(s - 1) * 4032 + k * 64 + b2];
                        else { float o1 = (k == 0) ? 1.f : 0.f; v = make_float2(o1, o1); }
                    } else if (k < 575)  v = cload2(&ctxT[(k - 63) * 64 + b2]);
                    else if (k < 1087)   v = cload2(&h0in[(k - 575) * 64 + b2]);
                    else                 v = make_float2(0.f, 0.f);
                    *(float2*)&xs[kk * 64 + b2] = v;
                }
#pragma unroll
                for (int i = 0; i < 4; ++i) {
                    int lidx = i * 256 + tid;
                    int rr = lidx >> 6, kk = lidx & 63;
                    int k = k0 + kk;
                    int g2 = rr >> 2, uu = rr & 3;
                    int jj = g2 * 512 + uid * 4 + uu;
                    float w;
                    if (k < 575)       w = wih0[(size_t)jj * 575 + k];
                    else if (k < 1087) w = whh0[(size_t)jj * 512 + (k - 575)];
                    else               w = 0.f;
                    ws[rr * 68 + kk] = w;
                }
                __syncthreads();
                const float* wsr = &ws[r * 68];
                const float* xsr = &xs[tb * 4];
#pragma unroll
                for (int kk = 0; kk < 64; ++kk) {
                    float wv = wsr[kk];
                    float4 x4 = *(const float4*)&xsr[kk * 64];
                    a0 = fmaf(wv, x4.x, a0);
                    a1 = fmaf(wv, x4.y, a1);
                    a2 = fmaf(wv, x4.z, a2);
                    a3 = fmaf(wv, x4.w, a3);
                }
            }
            {
                int g2 = r >> 2, uu = r & 3;
                int j = g2 * 512 + (blk >> 3) * 4 + uu;
                float bias = bih0[j] + bhh0[j];
                __syncthreads();
                *(float4*)&ex[r * 64 + tb * 4] =
                    make_float4(a0 + bias, a1 + bias, a2 + bias, a3 + bias);
            }
            __syncthreads();
            {
                int ui = tid >> 6, b = tid & 63;
                float gi = ex[(0 * 4 + ui) * 64 + b];
                float gf = ex[(1 * 4 + ui) * 64 + b];
                float gg = ex[(2 * 4 + ui) * 64 + b];
                float go = ex[(3 * 4 + ui) * 64 + b];
                float cn = sigm(gf) * c0reg + sigm(gi) * tanhf(gg);
                float hn = sigm(go) * tanhf(cn);
                c0reg = cn;
                cstore(&h0out[((blk >> 3) * 4 + ui) * 64 + b], hn);
            }
        } else if (role == 1 && s > 0) {
            int idx = blk >> 3;                  // 0..127
            int bcp = idx >> 1, chalf = idx & 1;
            float* xc = smem;                    // 1056 (padded)
#pragma unroll
            for (int i = 0; i < 2; ++i) {
                int k = (i * 256 + tid) * 2;
                float2 v = (k < 512) ? cload2(&h1b_prev[bcp * 512 + k])
                                     : cload2(&ctxb[bcp * 512 + (k - 512)]);
                int pk = k + (k >> 5);
                xc[pk] = v.x; xc[pk + 1] = v.y;
            }
            __syncthreads();
            int c8 = tid >> 3, kl = tid & 7;
            int c = chalf * 32 + c8;
            float p = 0.f;
            if (c < 63) {
                const float4* cw = (const float4*)&charw[(size_t)c * 1024 + kl * 128];
#pragma unroll
                for (int q = 0; q < 32; ++q) {
                    int k = kl * 128 + q * 4;
                    float4 w4 = cw[q];
                    const float* xp = &xc[k + (k >> 5)];
                    p = fmaf(xp[0], w4.x, p); p = fmaf(xp[1], w4.y, p);
                    p = fmaf(xp[2], w4.z, p); p = fmaf(xp[3], w4.w, p);
                }
            }
            p += __shfl_xor(p, 1, 64); p += __shfl_xor(p, 2, 64); p += __shfl_xor(p, 4, 64);
            if (kl == 0 && c < 63) cstore(&logit[bcp * 64 + c], p + charb[c]);
        }
        gbar(bar, epoch);

        // ==== phase B: LSTM1 (role 2) || preds-write(s-1) + colZero init (role 3) ====
        if (role == 2) {
            int uid = blk >> 3;
            float* xs = smem;
            float* ws = smem + 4096;
            float* ex = smem + 5184;
            int r = tid >> 4, tb = tid & 15;
            float a0 = 0.f, a1 = 0.f, a2 = 0.f, a3 = 0.f;
            for (int kc = 0; kc < 16; ++kc) {
                int k0 = kc * 64;
                __syncthreads();
#pragma unroll
                for (int i = 0; i < 8; ++i) {
                    int e2 = i * 256 + tid;
                    int kk = e2 >> 5, b2 = (e2 & 31) * 2;
                    int k = k0 + kk;
                    float2 v = (k < 512) ? cload2(&h0out[k * 64 + b2])
                                         : cload2(&h1in[(k - 512) * 64 + b2]);
                    *(float2*)&xs[kk * 64 + b2] = v;
                }
#pragma unroll
                for (int i = 0; i < 4; ++i) {
                    int lidx = i * 256 + tid;
                    int rr = lidx >> 6, kk = lidx & 63;
                    int k = k0 + kk;
                    int g2 = rr >> 2, uu = rr & 3;
                    int jj = g2 * 512 + uid * 4 + uu;
                    float w = (k < 512) ? wih1[(size_t)jj * 512 + k]
                                        : whh1[(size_t)jj * 512 + (k - 512)];
                    ws[rr * 68 + kk] = w;
                }
                __syncthreads();
                const float* wsr = &ws[r * 68];
                const float* xsr = &xs[tb * 4];
#pragma unroll
                for (int kk = 0; kk < 64; ++kk) {
                    float wv = wsr[kk];
                    float4 x4 = *(const float4*)&xsr[kk * 64];
                    a0 = fmaf(wv, x4.x, a0);
                    a1 = fmaf(wv, x4.y, a1);
                    a2 = fmaf(wv, x4.z, a2);
                    a3 = fmaf(wv, x4.w, a3);
                }
            }
            {
                int g2 = r >> 2, uu = r & 3;
                int j = g2 * 512 + uid * 4 + uu;
                float bias = bih1[j] + bhh1[j];
                __syncthreads();
                *(float4*)&ex[r * 64 + tb * 4] =
                    make_float4(a0 + bias, a1 + bias, a2 + bias, a3 + bias);
            }
            __syncthreads();
            {
                int ui = tid >> 6, b = tid & 63;
                float gi = ex[(0 * 4 + ui) * 64 + b];
                float gf = ex[(1 * 4 + ui) * 64 + b];
                float gg = ex[(2 * 4 + ui) * 64 + b];
                float go = ex[(3 * 4 + ui) * 64 + b];
                float cn = sigm(gf) * c1reg + sigm(gi) * tanhf(gg);
                float hn = sigm(go) * tanhf(cn);
                c1reg = cn;
                int u = uid * 4 + ui;
                cstore(&h1out[u * 64 + b], hn);
                cstore(&h1b_cur[b * 512 + u], hn);
            }
        } else if (role == 3) {
            int idx = blk >> 3;
            if (idx < 64) {
                if (s > 0 && tid < 64) {
                    int b = idx, c = tid;
                    float lg = (c < 63) ? cload(&logit[b * 64 + c]) : -1e30f;
                    float mx = lg;
                    for (int o = 32; o > 0; o >>= 1) mx = fmaxf(mx, __shfl_xor(mx, o, 64));
                    float ex2 = (c < 63) ? __expf(lg - mx) : 0.f;
                    float sume = wsum64(ex2);
                    if (c < 63)
                        preds[((size_t)(s - 1) * B_ + b) * CC + c] = lg - mx - __logf(sume);
                }
            } else {
                if (tid < 16) cstorei(&colZero[(idx - 64) * 16 + tid], 1);
            }
        }
        gbar(bar, epoch);

        // ==== phase CD: phi (redundant per block) + energy (512 blocks: b x 8 t-chunks) ====
        if ((blk & 1) == 0) {
            int idx = blk >> 1;                  // 0..511
            int b = idx >> 3, tc = idx & 7, t0 = tc * 128;
            float* xl = smem;                    // 512
            float* cdl = smem + 512;             // 256
            float* red = smem + 768;             // 512
            {
                float2 v = cload2(&h1b_cur[b * 512 + tid * 2]);
                *(float2*)&xl[tid * 2] = v;
            }
            __syncthreads();
            {
                float p = 0.f;
                const float4* wr = (const float4*)&phiw[(size_t)tid * 512];
#pragma unroll 8
                for (int q = 0; q < 128; ++q) {
                    float4 w4 = wr[q];
                    const float* xp = &xl[q * 4];
                    p = fmaf(xp[0], w4.x, p); p = fmaf(xp[1], w4.y, p);
                    p = fmaf(xp[2], w4.z, p); p = fmaf(xp[3], w4.w, p);
                }
                cdl[tid] = fmaxf(p + phib[tid], 0.f);
            }
            __syncthreads();
            int mh = tid >> 4, tg = tid & 15;
            int t8 = t0 + tg * 8;
            float acc[8] = {0.f, 0.f, 0.f, 0.f, 0.f, 0.f, 0.f, 0.f};
            const float* base = clT + ((size_t)(b * 256 + mh * 16)) * 1024 + t8;
#pragma unroll
            for (int m = 0; m < 16; ++m) {
                float4 v0 = *(const float4*)(base + (size_t)m * 1024);
                float4 v1 = *(const float4*)(base + (size_t)m * 1024 + 4);
                float c = cdl[mh * 16 + m];
                acc[0] = fmaf(c, v0.x, acc[0]);
                acc[1] = fmaf(c, v0.y, acc[1]);
                acc[2] = fmaf(c, v0.z, acc[2]);
                acc[3] = fmaf(c, v0.w, acc[3]);
                acc[4] = fmaf(c, v1.x, acc[4]);
                acc[5] = fmaf(c, v1.y, acc[5]);
                acc[6] = fmaf(c, v1.z, acc[6]);
                acc[7] = fmaf(c, v1.w, acc[7]);
            }
#pragma unroll
            for (int j = 0; j < 8; ++j) {
                acc[j] += __shfl_xor(acc[j], 16, 64);
                acc[j] += __shfl_xor(acc[j], 32, 64);
            }
            int w = tid >> 6;
            if (((tid >> 4) & 3) == 0) {
#pragma unroll
                for (int j = 0; j < 8; ++j) red[w * 128 + tg * 8 + j] = acc[j];
            }
            __syncthreads();
            if (tid < 128) {
                float sum = red[tid] + red[128 + tid] + red[256 + tid] + red[384 + tid];
                int t = t0 + tid;
                cstore(&energyT[t * 64 + b], sum);
                if (sum != 0.f) cstorei(&colZero[t], 0);
            }
        }
        gbar(bar, epoch);

        // ==== phase E: copula stats + vals (256 blocks, 4 t each; r6-verbatim math) ====
        if ((blk & 3) == 0) {
            int idx = blk >> 2;                  // 0..255
            int* zred = (int*)smem;
            int zacc = cloadi(&colZero[tid]) | cloadi(&colZero[256 + tid])
                     | cloadi(&colZero[512 + tid]) | cloadi(&colZero[768 + tid]);
            zred[tid] = zacc;
            __syncthreads();
            for (int o = 128; o > 0; o >>= 1) {
                if (tid < o) zred[tid] |= zred[tid + o];
                __syncthreads();
            }
            int zf = zred[0];
            int wv = tid >> 6, b = tid & 63;
            int t = idx * 4 + wv;
            float e = cload(&energyT[t * 64 + b]);
            float a = (t > 0) ? cload(&energyT[(t - 1) * 64 + b]) : 0.f;
            float val;
            if (zf) {
                val = e;
            } else {
                float cp;
                if (t >= 1 && t < 1023) {
                    float ma = wsum64(a) * (1.f / 64.f);
                    float mb = wsum64(e) * (1.f / 64.f);
                    float am = a - ma, bm = e - mb;
                    float sab = wsum64(am * bm);
                    float saa = wsum64(am * am);
                    float sbb = wsum64(bm * bm);
                    int aeq = __all(a == e);
                    float r = sab / sqrtf(saa * sbb + 1e-12f);
                    float det = 1.f - r * r;
                    if (det < 0.01f || aeq) cp = 10.f;
                    else {
                        float ds = fmaxf(det, 1e-6f);
                        float quad = r * r * (a * a + e * e) - 2.f * r * a * e;
                        cp = __expf(-0.5f * quad / ds) / sqrtf(ds);
                    }
                } else {
                    cp = 1.f;
                }
                float pdf = __expf(-0.5f * e * e) * INV_SQRT_2PI;
                val = pdf * cp;
            }
            cstore(&vbuf[b * 1024 + t], val);
        }
        gbar(bar, epoch);

        // ==== phase F: softmax + atts + context (1024 blocks: b x 16 d-chunks of 32) ====
        {
            int b = blk >> 4, dq = blk & 15, d0 = dq * 32;
            float* red = smem;           // 256
            float* red2 = smem + 256;    // 128
            float2 w0 = cload2(&vbuf[b * 1024 + tid * 4]);
            float2 w1 = cload2(&vbuf[b * 1024 + tid * 4 + 2]);
            float4 v4 = make_float4(w0.x, w0.y, w1.x, w1.y);
            float lm = fmaxf(fmaxf(v4.x, v4.y), fmaxf(v4.z, v4.w));
            red[tid] = lm;
            __syncthreads();
            for (int o = 128; o > 0; o >>= 1) {
                if (tid < o) red[tid] = fmaxf(red[tid], red[tid + o]);
                __syncthreads();
            }
            float M = red[0];
            __syncthreads();
            float e0 = __expf(v4.x - M), e1 = __expf(v4.y - M);
            float e2 = __expf(v4.z - M), e3 = __expf(v4.w - M);
            red[tid] = e0 + e1 + e2 + e3;
            __syncthreads();
            for (int o = 128; o > 0; o >>= 1) {
                if (tid < o) red[tid] += red[tid + o];
                __syncthreads();
            }
            float inv = 1.f / red[0];
            float4 a4 = make_float4(e0 * inv, e1 * inv, e2 * inv, e3 * inv);
            if (dq == 0)
                *(float4*)&atts[((size_t)s * B_ + b) * 1024 + tid * 4] = a4;
            __syncthreads();
            int tc = tid >> 2, dg = tid & 3;
            int d8 = d0 + dg * 8;
            float acc[8] = {0.f, 0.f, 0.f, 0.f, 0.f, 0.f, 0.f, 0.f};
            const unsigned short* Lb = Lbf + (size_t)b * 524288 + (size_t)(tc * 16) * 512 + d8;
#pragma unroll
            for (int q = 0; q < 4; ++q) {
                int src = (tc * 4 + q) & 63;
                float av0 = __shfl(a4.x, src, 64);
                float av1 = __shfl(a4.y, src, 64);
                float av2 = __shfl(a4.z, src, 64);
                float av3 = __shfl(a4.w, src, 64);
                float avs[4] = {av0, av1, av2, av3};
#pragma unroll
                for (int e = 0; e < 4; ++e) {
                    float wv2 = avs[e];
                    short8v v = *(const short8v*)(Lb + (size_t)(q * 4 + e) * 512);
                    acc[0] = fmaf(wv2, bf2f((unsigned short)v[0]), acc[0]);
                    acc[1] = fmaf(wv2, bf2f((unsigned short)v[1]), acc[1]);
                    acc[2] = fmaf(wv2, bf2f((unsigned short)v[2]), acc[2]);
                    acc[3] = fmaf(wv2, bf2f((unsigned short)v[3]), acc[3]);
                    acc[4] = fmaf(wv2, bf2f((unsigned short)v[4]), acc[4]);
                    acc[5] = fmaf(wv2, bf2f((unsigned short)v[5]), acc[5]);
                    acc[6] = fmaf(wv2, bf2f((unsigned short)v[6]), acc[6]);
                    acc[7] = fmaf(wv2, bf2f((unsigned short)v[7]), acc[7]);
                }
            }
#pragma unroll
            for (int j = 0; j < 8; ++j) {
                acc[j] += __shfl_xor(acc[j], 4, 64);
                acc[j] += __shfl_xor(acc[j], 8, 64);
                acc[j] += __shfl_xor(acc[j], 16, 64);
                acc[j] += __shfl_xor(acc[j], 32, 64);
            }
            int w = tid >> 6;
            if ((tid & 60) == 0) {
#pragma unroll
                for (int j = 0; j < 8; ++j) red2[w * 32 + dg * 8 + j] = acc[j];
            }
            __syncthreads();
            if (tid < 32) {
                float cv = red2[tid] + red2[32 + tid] + red2[64 + tid] + red2[96 + tid];
                cstore(&ctxT[(d0 + tid) * 64 + b], cv);
                cstore(&ctxb[b * 512 + d0 + tid], cv);
            }
        }
        gbar(bar, epoch);
    }

    // ---- tail: char-logits(63) then preds(63) ----
    if (role == 1) {
        int idx = blk >> 3;
        int bcp = idx >> 1, chalf = idx & 1;
        float* xc = smem;
#pragma unroll
        for (int i = 0; i < 2; ++i) {
            int k = (i * 256 + tid) * 2;
            float2 v = (k < 512) ? cload2(&h1bb[bcp * 512 + k])
                                 : cload2(&ctxb[bcp * 512 + (k - 512)]);
            int pk = k + (k >> 5);
            xc[pk] = v.x; xc[pk + 1] = v.y;
        }
        __syncthreads();
        int c8 = tid >> 3, kl = tid & 7;
        int c = chalf * 32 + c8;
        float p = 0.f;
        if (c < 63) {
            const float4* cw = (const float4*)&charw[(size_t)c * 1024 + kl * 128];
#pragma unroll
            for (int q = 0; q < 32; ++q) {
                int k = kl * 128 + q * 4;
                float4 w4 = cw[q];
                const float* xp = &xc[k + (k >> 5)];
                p = fmaf(xp[0], w4.x, p); p = fmaf(xp[1], w4.y, p);
                p = fmaf(xp[2], w4.z, p); p = fmaf(xp[3], w4.w, p);
            }
        }
        p += __shfl_xor(p, 1, 64); p += __shfl_xor(p, 2, 64); p += __shfl_xor(p, 4, 64);
        if (kl == 0 && c < 63) cstore(&logit[bcp * 64 + c], p + charb[c]);
    }
    gbar(bar, epoch);
    if (blk < 64 && tid < 64) {
        int b = blk, c = tid;
        float lg = (c < 63) ? cload(&logit[b * 64 + c]) : -1e30f;
        float mx = lg;
        for (int o = 32; o > 0; o >>= 1) mx = fmaxf(mx, __shfl_xor(mx, o, 64));
        float ex2 = (c < 63) ? __expf(lg - mx) : 0.f;
        float sume = wsum64(ex2);
        if (c < 63)
            preds[((size_t)(SS - 1) * B_ + b) * CC + c] = lg - mx - __logf(sume);
    }
}

extern "C" void kernel_launch(void* const* d_in, const int* in_sizes, int n_in,
                              void* d_out, int out_size, void* d_ws, size_t ws_size,
                              hipStream_t stream) {
    const float* Lf   = (const float*)d_in[0];
    const float* gt   = (const float*)d_in[1];
    const float* phiw = (const float*)d_in[2];
    const float* phib = (const float*)d_in[3];
    const float* psiw = (const float*)d_in[4];
    const float* psib = (const float*)d_in[5];
    const float* wih0 = (const float*)d_in[6];
    const float* whh0 = (const float*)d_in[7];
    const float* bih0 = (const float*)d_in[8];
    const float* bhh0 = (const float*)d_in[9];
    const float* wih1 = (const float*)d_in[10];
    const float* whh1 = (const float*)d_in[11];
    const float* bih1 = (const float*)d_in[12];
    const float* bhh1 = (const float*)d_in[13];
    const float* charw = (const float*)d_in[14];
    const float* charb = (const float*)d_in[15];

    float* preds = (float*)d_out;
    float* atts  = (float*)d_out + (size_t)SS * B_ * CC;

    char* ws = (char*)d_ws;
    size_t off = 0;
    auto alloc = [&](size_t bytes) { size_t o = off; off = (off + bytes + 255) & ~(size_t)255; return o; };
    float* clT     = (float*)(ws + alloc((size_t)B_ * M_ * T_ * 4));
    unsigned short* Lbf = (unsigned short*)(ws + alloc((size_t)B_ * T_ * D_ * 2));
    float* gtT     = (float*)(ws + alloc((size_t)SS * CC * 64 * 4));
    float* h0buf   = (float*)(ws + alloc(2 * H_ * B_ * 4));
    float* h1buf   = (float*)(ws + alloc(2 * H_ * B_ * 4));
    float* h1bb    = (float*)(ws + alloc(2 * H_ * B_ * 4));
    float* ctxT    = (float*)(ws + alloc(H_ * B_ * 4));
    float* ctxb    = (float*)(ws + alloc(H_ * B_ * 4));
    float* energyT = (float*)(ws + alloc(B_ * T_ * 4));
    float* vbuf    = (float*)(ws + alloc(B_ * T_ * 4));
    float* logit   = (float*)(ws + alloc(B_ * 64 * 4));
    int* colZero   = (int*)(ws + alloc(1024 * 4));
    int* bar       = (int*)(ws + alloc(2048 * 4));

    hipMemsetAsync(bar, 0, 2048 * 4, stream);
    k_gemm<<<4096, 256, 0, stream>>>(Lf, psiw, psib, clT);
    k_conv<<<2048, 256, 0, stream>>>(Lf, Lbf, (B_ * T_ * D_) / 4);
    k_mega<<<NBLK, 256, 0, stream>>>(Lbf, Lf, gt,
                                     phiw, phib, wih0, whh0, bih0, bhh0,
                                     wih1, whh1, bih1, bhh1, charw, charb,
                                     clT, gtT, h0buf, h1buf, h1bb,
                                     ctxT, ctxb, energyT, vbuf,
                                     logit, colZero, bar, preds, atts);
}